// Round 7
// baseline (374.853 us; speedup 1.0000x reference)
//
#include <hip/hip_runtime.h>

// GenLSTM: B=8192, T=256 (255 steps), noise=8, seq_dim=4, HID=64, gates=256.
// R12 = R11 + non-draining barriers. R11 post-mortem: skew+setprio confirmed the
// convoy theory (-10%, VALU 50->56, Mfma 26->29). Remaining stall: __syncthreads
// compiles to s_waitcnt vmcnt(0) lgkmcnt(0) + s_barrier, so B1 DRAINS the
// in-flight noise prefetch (streamed, L2-missing, ~900cyc) every step -- the
// "one step ahead" prefetch never survived the first barrier. Fix:
// (1) raw barrier waiting on LDS only: asm("s_waitcnt lgkmcnt(0); s_barrier")
//     with "memory" clobber (HK T4 pattern). Global noise loads now ride across
//     all 3 barriers to their tail use; wave0's output stores never drain.
// (2) tail reorder: noise MFMAs (register-ready) BEFORE W3W MFMAs (wait on y2
//     ds_read) -> post-B3 chain is ds_read -> 2 dep MFMAs, not 3.
// Kept from R11: anti-convoy s_sleep skew (bit8), setprio 1 over the MFMA/LDS
// phase, R5 skeleton (512x256, M=16, 2 blocks/CU), W3W fold, register noise
// B-frag, bias b' in wgn row k=8 (B=1 via quad1 nf0.x), exp2-prescaled gates,
// 7-trans cell, prologue bias via transient loads.

typedef _Float16 h8 __attribute__((ext_vector_type(8)));
typedef __fp16 p2h __attribute__((ext_vector_type(2)));
typedef float f4 __attribute__((ext_vector_type(4)));

#define MFMA(a, b, c) __builtin_amdgcn_mfma_f32_16x16x32_f16(a, b, c, 0, 0, 0)
#define EXP2(x) __builtin_amdgcn_exp2f(x)
// LDS-only barrier: do NOT drain vmcnt (in-flight global prefetch/stores ride).
#define BAR_LDS() asm volatile("s_waitcnt lgkmcnt(0)\n\ts_barrier" ::: "memory")

constexpr int SEQ = 256, STEPS = 255, ND = 8, SD = 4, HID = 64, G4 = 256;
constexpr int HST = 72;  // h/y row stride (f16): 16B-aligned rows
constexpr float LOG2E = 1.44269504f;

__device__ __forceinline__ void store4h(_Float16* p, f4 v) {
    p2h lo = __builtin_amdgcn_cvt_pkrtz(v[0], v[1]);
    p2h hi = __builtin_amdgcn_cvt_pkrtz(v[2], v[3]);
    float2 st;
    st.x = __builtin_bit_cast(float, lo);
    st.y = __builtin_bit_cast(float, hi);
    *(float2*)p = st;
}

__global__ __launch_bounds__(256, 2) void genlstm_kernel(
    const float* __restrict__ noise, const float* __restrict__ Wx,
    const float* __restrict__ Wh, const float* __restrict__ b,
    const float* __restrict__ W1, const float* __restrict__ b1,
    const float* __restrict__ W2, const float* __restrict__ b2,
    const float* __restrict__ W3, const float* __restrict__ b3,
    float* __restrict__ out)
{
    __shared__ alignas(16) _Float16 Hb[16 * HST];
    __shared__ alignas(16) _Float16 Y1b[16 * HST];
    __shared__ alignas(16) _Float16 Y2b[16 * HST];

    const int tid = threadIdx.x, wid = tid >> 6, lane = tid & 63;
    const int col = lane & 15, quad = lane >> 4, q8 = quad * 8;
    const int row0 = blockIdx.x * 16;
    const int n0 = wid * 16 + col;       // gate/hid col for weight frags
    const int wq = wid * 16 + quad * 4;  // C^T write col base

    const float gsc[4] = {LOG2E, LOG2E, 2.f * LOG2E, LOG2E};  // i,f,g,o

    // ---- gate weight frags: Wh slices (k=0..63), exp2-prescaled ----
    h8 wg[4][2];
    #pragma unroll
    for (int g = 0; g < 4; ++g)
        #pragma unroll
        for (int s = 0; s < 2; ++s)
            #pragma unroll
            for (int j = 0; j < 8; ++j)
                wg[g][s][j] = (_Float16)(Wh[(32 * s + q8 + j) * G4 + 64 * g + n0] * gsc[g]);

    // ---- noise+bias slice: k=0..7 -> Wxn rows (quad0), k=8 -> b' row (quad1 j=0) ----
    // b' = b + b3 @ Wx_x  (the x-fold bias), prescaled.
    h8 wgn[4];
    #pragma unroll
    for (int g = 0; g < 4; ++g)
        #pragma unroll
        for (int j = 0; j < 8; ++j) {
            const int k = q8 + j;
            const int n = 64 * g + n0;
            float v = 0.0f;
            if (k < 8) v = Wx[(4 + k) * G4 + n];
            else if (k == 8) {
                float bx = b3[0] * Wx[0 * G4 + n] + b3[1] * Wx[1 * G4 + n] +
                           b3[2] * Wx[2 * G4 + n] + b3[3] * Wx[3 * G4 + n];
                v = b[n] + bx;
            }
            wgn[g][j] = (_Float16)(v * gsc[g]);
        }

    // ---- W3W = W3 @ Wx[0:4,:] fold (prescaled): z += y2 @ W3W ----
    h8 wgy[4][2];
    #pragma unroll
    for (int s = 0; s < 2; ++s)
        #pragma unroll
        for (int j = 0; j < 8; ++j) {
            const int k = 32 * s + q8 + j;
            const float w30 = W3[k * SD + 0], w31 = W3[k * SD + 1];
            const float w32 = W3[k * SD + 2], w33 = W3[k * SD + 3];
            #pragma unroll
            for (int g = 0; g < 4; ++g) {
                const int n = 64 * g + n0;
                float acc = w30 * Wx[0 * G4 + n] + w31 * Wx[1 * G4 + n] +
                            w32 * Wx[2 * G4 + n] + w33 * Wx[3 * G4 + n];
                wgy[g][s][j] = (_Float16)(acc * gsc[g]);
            }
        }
    // ---- MLP weight frags (wave-split, 16 cols each) ----
    h8 w1f[2], w2f[2], w3f[2];
    #pragma unroll
    for (int s = 0; s < 2; ++s)
        #pragma unroll
        for (int j = 0; j < 8; ++j) {
            const int k = 32 * s + q8 + j;
            w1f[s][j] = (_Float16)W1[k * HID + n0];
            w2f[s][j] = (_Float16)W2[k * HID + n0];
            w3f[s][j] = (_Float16)(col < 4 ? W3[k * SD + col] : 0.0f);
        }
    f4 b1v, b2v, b3v;
    #pragma unroll
    for (int r = 0; r < 4; ++r) {
        b1v[r] = b1[wq + r];
        b2v[r] = b2[wq + r];
        b3v[r] = (quad == 0) ? b3[r] : 0.0f;
    }

    if (tid < 16) {  // out[:,0,:] = 0
        float4 z; z.x = z.y = z.z = z.w = 0.0f;
        *(float4*)(out + (size_t)(row0 + tid) * SEQ * SD) = z;
    }

    _Float16* Hrow = &Hb[col * HST];
    _Float16* Y1row = &Y1b[col * HST];
    _Float16* Y2row = &Y2b[col * HST];
    float* outp = out + ((size_t)(row0 + col) * SEQ + 1) * SD;

    // noise: quad0 lanes own all 8 dims of batch row (row0+col)
    const float* npt = noise + (size_t)(row0 + col) * SEQ * ND;

    const f4 fz = {0.f, 0.f, 0.f, 0.f};
    f4 cst = fz, run = fz;
    f4 zi, zf, zg, zo;

    // nf persists across iterations; only quad0 reloads it. After the prologue,
    // quad1's nf0.x becomes the constant 1.0 feeding the b' bias row (k=8).
    float4 nf0, nf1;
    nf0.x = nf0.y = nf0.z = nf0.w = 0.f;
    nf1 = nf0;

    // ---- anti-convoy skew: co-resident pair = (b, b+256) under XCD
    // round-robin dispatch; shift slot-1 blocks by ~half a step so the pair
    // runs anti-phase (cell-VALU vs MFMA/LDS windows). ----
    if (blockIdx.x & 256) __builtin_amdgcn_s_sleep(26);

    // ---- prologue: z(0) = noise(0) @ Wxn + b  (h(0)=0, x(0)=0; bias slot 0) ----
    {
        if (quad == 0) { nf0 = *(const float4*)npt; nf1 = *(const float4*)(npt + 4); }
        npt += ND;
        union { h8 v; p2h p[4]; } nb;
        nb.p[0] = __builtin_amdgcn_cvt_pkrtz(nf0.x, nf0.y);
        nb.p[1] = __builtin_amdgcn_cvt_pkrtz(nf0.z, nf0.w);
        nb.p[2] = __builtin_amdgcn_cvt_pkrtz(nf1.x, nf1.y);
        nb.p[3] = __builtin_amdgcn_cvt_pkrtz(nf1.z, nf1.w);
        // transient prologue bias b*gsc (dead after this block)
        #pragma unroll
        for (int g = 0; g < 4; ++g) {
            f4 tb;
            #pragma unroll
            for (int r = 0; r < 4; ++r) tb[r] = b[64 * g + wq + r] * gsc[g];
            f4 z0 = MFMA(wgn[g], nb.v, tb);
            if (g == 0) zi = z0; else if (g == 1) zf = z0;
            else if (g == 2) zg = z0; else zo = z0;
        }
        if (quad == 1) nf0.x = 1.0f;  // enable the b' bias row from step 1 on
    }

    #pragma unroll 1
    for (int t = 0; t < STEPS; ++t) {
        // prefetch noise(t+1): issued here, consumed at the tail. With BAR_LDS
        // (no vmcnt drain) it genuinely rides across all three barriers.
        if (quad == 0) { nf0 = *(const float4*)npt; nf1 = *(const float4*)(npt + 4); }
        npt += ND;

        // ---- cell update from complete z(t); 7 trans, exp2-prescaled ----
        f4 hv;
        #pragma unroll
        for (int r = 0; r < 4; ++r) {
            float Ei = EXP2(-fmaxf(zi[r], -15.f * LOG2E));
            float Ef = EXP2(-fmaxf(zf[r], -15.f * LOG2E));
            float Eg = EXP2(-fmaxf(zg[r], -30.f * LOG2E));
            float Eo = EXP2(-zo[r]);
            float Di = 1.f + Ei, Df = 1.f + Ef, Dg = 1.f + Eg, Do = 1.f + Eo;
            float DiDg = Di * Dg;
            float cn = (cst[r] * DiDg + (2.f - Dg) * Df) *
                       __builtin_amdgcn_rcpf(Df * DiDg);
            cst[r] = cn;
            float Ec = EXP2(fmaxf(cn, -15.f) * (-2.f * LOG2E));
            hv[r] = (1.f - Ec) * __builtin_amdgcn_rcpf(Do * (1.f + Ec));
        }
        store4h(Hrow + wq, hv);  // h(t+1)
        BAR_LDS();  // B1

        __builtin_amdgcn_s_setprio(1);  // MFMA/LDS phase begins

        h8 h0 = *(const h8*)(&Hb[col * HST] + q8);
        h8 h1 = *(const h8*)(&Hb[col * HST] + 32 + q8);

        // ---- y1 = relu(h @ W1 + b1) ----
        f4 y1 = MFMA(w1f[0], h0, b1v);
        y1 = MFMA(w1f[1], h1, y1);
        #pragma unroll
        for (int r = 0; r < 4; ++r) y1[r] = fmaxf(y1[r], 0.f);
        store4h(Y1row + wq, y1);

        // pipelined gate-h for z(t+1); C-init = shared zero (bias rides in wgn)
        zi = MFMA(wg[0][0], h0, fz); zi = MFMA(wg[0][1], h1, zi);
        zf = MFMA(wg[1][0], h0, fz); zf = MFMA(wg[1][1], h1, zf);
        zg = MFMA(wg[2][0], h0, fz); zg = MFMA(wg[2][1], h1, zg);
        zo = MFMA(wg[3][0], h0, fz); zo = MFMA(wg[3][1], h1, zo);
        BAR_LDS();  // B2

        // ---- y2 = relu(y1 @ W2 + b2) ----
        h8 p0 = *(const h8*)(Y1row + q8);
        h8 p1 = *(const h8*)(Y1row + 32 + q8);
        f4 y2 = MFMA(w2f[0], p0, b2v);
        y2 = MFMA(w2f[1], p1, y2);
        #pragma unroll
        for (int r = 0; r < 4; ++r) y2[r] = fmaxf(y2[r], 0.f);
        store4h(Y2row + wq, y2);
        BAR_LDS();  // B3

        // issue y2 reads first, then do register-ready noise MFMAs while the
        // ds_read completes: post-B3 dep chain is ds_read -> 2 MFMAs.
        h8 q0 = *(const h8*)(Y2row + q8);
        h8 q1 = *(const h8*)(Y2row + 32 + q8);

        // ---- z(t+1) += noise(t+1) @ Wxn + b' (prefetched regs; bias row k=8) ----
        union { h8 v; p2h p[4]; } nb;
        nb.p[0] = __builtin_amdgcn_cvt_pkrtz(nf0.x, nf0.y);
        nb.p[1] = __builtin_amdgcn_cvt_pkrtz(nf0.z, nf0.w);
        nb.p[2] = __builtin_amdgcn_cvt_pkrtz(nf1.x, nf1.y);
        nb.p[3] = __builtin_amdgcn_cvt_pkrtz(nf1.z, nf1.w);
        zi = MFMA(wgn[0], nb.v, zi);
        zf = MFMA(wgn[1], nb.v, zf);
        zg = MFMA(wgn[2], nb.v, zg);
        zo = MFMA(wgn[3], nb.v, zo);

        // ---- z(t+1) += y2 @ W3W  (the folded x-contribution) ----
        zi = MFMA(wgy[0][0], q0, zi); zi = MFMA(wgy[0][1], q1, zi);
        zf = MFMA(wgy[1][0], q0, zf); zf = MFMA(wgy[1][1], q1, zf);
        zg = MFMA(wgy[2][0], q0, zg); zg = MFMA(wgy[2][1], q1, zg);
        zo = MFMA(wgy[3][0], q0, zo); zo = MFMA(wgy[3][1], q1, zo);

        // ---- x(t+1) = y2 @ W3 + b3: output only, wave 0 only, off-path ----
        if (wid == 0) {
            f4 x = MFMA(w3f[0], q0, b3v);
            x = MFMA(w3f[1], q1, x);
            if (quad == 0) {
                run += x;
                *(f4*)outp = run;  // cumsum output, dwordx4
            }
        }
        outp += SD;

        __builtin_amdgcn_s_setprio(0);  // back to VALU phase (cell of t+1)
    }
}

extern "C" void kernel_launch(void* const* d_in, const int* in_sizes, int n_in,
                              void* d_out, int out_size, void* d_ws, size_t ws_size,
                              hipStream_t stream) {
    genlstm_kernel<<<512, 256, 0, stream>>>(
        (const float*)d_in[0], (const float*)d_in[1], (const float*)d_in[2],
        (const float*)d_in[3], (const float*)d_in[4], (const float*)d_in[5],
        (const float*)d_in[6], (const float*)d_in[7], (const float*)d_in[8],
        (const float*)d_in[9], (float*)d_out);
}